// Round 5
// baseline (121.861 us; speedup 1.0000x reference)
//
#include <hip/hip_runtime.h>

// ROI align-style pooling (bilinear), matches reference _pool_one_roi exactly.
// img: (1,128,128,1024) f32, rois: (1,256,4) f32 (x,y,w,h in pixels)
// out: (1,256,7,7,1024) f32
//
// R4: XCD-aware block swizzle. Flat grid 12544 blocks; dispatcher round-robins
//     flat id across 8 XCDs, so we map b=(j*8+k) -> XCD k handles ROIs
//     [k*32, k*32+32). All 49 cells of a ROI share ~4x corner rows -> keep
//     them in one XCD's 4MB L2 instead of scattering across 8 L2s.
//     Compute structure unchanged from R3 (128 thr x 8 ch, regular stores).

#define IMG_H 128
#define IMG_W 128
#define IMG_C 1024
#define POOLK 7
#define NROIS 256
#define NXCD 8

typedef float vfloat4 __attribute__((ext_vector_type(4)));

__device__ __forceinline__ vfloat4 lerp2d(vfloat4 v00, vfloat4 v01,
                                          vfloat4 v10, vfloat4 v11,
                                          float tx, float ty) {
  vfloat4 top = v00 + tx * (v01 - v00);
  vfloat4 bot = v10 + tx * (v11 - v10);
  return top + ty * (bot - top);
}

__global__ __launch_bounds__(128) void roi_pool_kernel(
    const float* __restrict__ img,
    const float* __restrict__ rois,
    float* __restrict__ out) {
  // Swizzle: b = j*8 + k.  XCD k gets ROIs [k*32, (k+1)*32), cell = j % 49.
  const int b = blockIdx.x;             // 0..12543
  const int k = b & (NXCD - 1);         // XCD slot
  const int j = b >> 3;                 // 0..1567  (= 32 ROIs * 49 cells)
  const int r = k * (NROIS / NXCD) + j / (POOLK * POOLK);
  const int cell = j % (POOLK * POOLK);
  const int iy = cell / POOLK;
  const int ix = cell % POOLK;

  // Uniform per-block geometry (redundant per-thread compute is cheap).
  const vfloat4 roi = *(const vfloat4*)(rois + (size_t)r * 4);

  // c = (roi * SCALE).astype(int32): non-negative, trunc == floor.
  const int x0 = (int)(roi.x * 0.0625f);
  const int y0 = (int)(roi.y * 0.0625f);
  const int w  = (int)(roi.z * 0.0625f);
  const int h  = (int)(roi.w * 0.0625f);

  // Match reference op order: (h_f / POOL) first, then multiply by i.
  const float sy = (float)iy * ((float)h / 7.0f);
  const float sx = (float)ix * ((float)w / 7.0f);
  const float fy = floorf(sy);
  const float fx = floorf(sx);
  const float ty = sy - fy;
  const float tx = sx - fx;
  const int y_lo = (int)fy;
  const int x_lo = (int)fx;
  const int y_hi = min(y_lo + 1, max(h - 1, 0));
  const int x_hi = min(x_lo + 1, max(w - 1, 0));
  const int gy0 = min(max(y0 + y_lo, 0), IMG_H - 1);
  const int gy1 = min(max(y0 + y_hi, 0), IMG_H - 1);
  const int gx0 = min(max(x0 + x_lo, 0), IMG_W - 1);
  const int gx1 = min(max(x0 + x_hi, 0), IMG_W - 1);

  const int c = threadIdx.x * 8;  // 128 threads x 8 channels = 1024

  const float* p00 = img + ((size_t)(gy0 * IMG_W + gx0)) * IMG_C + c;
  const float* p01 = img + ((size_t)(gy0 * IMG_W + gx1)) * IMG_C + c;
  const float* p10 = img + ((size_t)(gy1 * IMG_W + gx0)) * IMG_C + c;
  const float* p11 = img + ((size_t)(gy1 * IMG_W + gx1)) * IMG_C + c;

  // 8 independent 16B loads in flight.
  const vfloat4 a00 = *(const vfloat4*)(p00);
  const vfloat4 b00 = *(const vfloat4*)(p00 + 4);
  const vfloat4 a01 = *(const vfloat4*)(p01);
  const vfloat4 b01 = *(const vfloat4*)(p01 + 4);
  const vfloat4 a10 = *(const vfloat4*)(p10);
  const vfloat4 b10 = *(const vfloat4*)(p10 + 4);
  const vfloat4 a11 = *(const vfloat4*)(p11);
  const vfloat4 b11 = *(const vfloat4*)(p11 + 4);

  const vfloat4 oa = lerp2d(a00, a01, a10, a11, tx, ty);
  const vfloat4 ob = lerp2d(b00, b01, b10, b11, tx, ty);

  float* op = out + (((size_t)r * POOLK + iy) * POOLK + ix) * IMG_C + c;
  *(vfloat4*)op = oa;
  *(vfloat4*)(op + 4) = ob;
}

extern "C" void kernel_launch(void* const* d_in, const int* in_sizes, int n_in,
                              void* d_out, int out_size, void* d_ws, size_t ws_size,
                              hipStream_t stream) {
  const float* img  = (const float*)d_in[0];   // 1*128*128*1024
  const float* rois = (const float*)d_in[1];   // 1*256*4
  float* out = (float*)d_out;                  // 1*256*7*7*1024

  dim3 grid(POOLK * POOLK * NROIS);  // 12544 flat, swizzled in-kernel
  dim3 block(128);
  roi_pool_kernel<<<grid, block, 0, stream>>>(img, rois, out);
}

// Round 6
// 119.583 us; speedup vs baseline: 1.0191x; 1.0191x over previous
//
#include <hip/hip_runtime.h>

// ROI align-style pooling (bilinear), matches reference _pool_one_roi exactly.
// img: (1,128,128,1024) f32, rois: (1,256,4) f32 (x,y,w,h in pixels)
// out: (1,256,7,7,1024) f32
//
// R5: strip-per-block. One block per (roi, iy): 1792 blocks x 256 threads,
//     loop ix=0..6. Y-rows fixed per strip, consecutive ix share corner
//     pixels -> L1-level reuse (vs L2-level with 12544 cell-blocks), 7x
//     fewer block dispatches, load pipeline across ix iterations.

#define IMG_H 128
#define IMG_W 128
#define IMG_C 1024
#define POOLK 7
#define NROIS 256

typedef float vfloat4 __attribute__((ext_vector_type(4)));

__global__ __launch_bounds__(256) void roi_pool_kernel(
    const float* __restrict__ img,
    const float* __restrict__ rois,
    float* __restrict__ out) {
  const int iy = blockIdx.x;   // 0..6
  const int r  = blockIdx.y;   // 0..255

  const vfloat4 roi = *(const vfloat4*)(rois + (size_t)r * 4);

  // c = (roi * SCALE).astype(int32): non-negative, trunc == floor.
  const int x0 = (int)(roi.x * 0.0625f);
  const int y0 = (int)(roi.y * 0.0625f);
  const int w  = (int)(roi.z * 0.0625f);
  const int h  = (int)(roi.w * 0.0625f);

  // y geometry fixed for the whole strip.
  const float sy = (float)iy * ((float)h / 7.0f);
  const float fy = floorf(sy);
  const float ty = sy - fy;
  const int y_lo = (int)fy;
  const int y_hi = min(y_lo + 1, max(h - 1, 0));
  const int gy0 = min(max(y0 + y_lo, 0), IMG_H - 1);
  const int gy1 = min(max(y0 + y_hi, 0), IMG_H - 1);

  const int c = threadIdx.x * 4;  // 256 threads x float4 = 1024 channels
  const float* row0 = img + (size_t)gy0 * (IMG_W * IMG_C) + c;
  const float* row1 = img + (size_t)gy1 * (IMG_W * IMG_C) + c;
  float* orow = out + (((size_t)r * POOLK + iy) * POOLK) * IMG_C + c;

  const float step_x = (float)w / 7.0f;
  const int xmax = max(w - 1, 0);

#pragma unroll
  for (int ix = 0; ix < POOLK; ++ix) {
    const float sx = (float)ix * step_x;
    const float fx = floorf(sx);
    const float tx = sx - fx;
    const int x_lo = (int)fx;
    const int x_hi = min(x_lo + 1, xmax);
    const int gx0 = min(max(x0 + x_lo, 0), IMG_W - 1);
    const int gx1 = min(max(x0 + x_hi, 0), IMG_W - 1);

    const vfloat4 v00 = *(const vfloat4*)(row0 + (size_t)gx0 * IMG_C);
    const vfloat4 v01 = *(const vfloat4*)(row0 + (size_t)gx1 * IMG_C);
    const vfloat4 v10 = *(const vfloat4*)(row1 + (size_t)gx0 * IMG_C);
    const vfloat4 v11 = *(const vfloat4*)(row1 + (size_t)gx1 * IMG_C);

    const vfloat4 top = v00 + tx * (v01 - v00);
    const vfloat4 bot = v10 + tx * (v11 - v10);
    const vfloat4 o   = top + ty * (bot - top);

    *(vfloat4*)(orow + (size_t)ix * IMG_C) = o;
  }
}

extern "C" void kernel_launch(void* const* d_in, const int* in_sizes, int n_in,
                              void* d_out, int out_size, void* d_ws, size_t ws_size,
                              hipStream_t stream) {
  const float* img  = (const float*)d_in[0];   // 1*128*128*1024
  const float* rois = (const float*)d_in[1];   // 1*256*4
  float* out = (float*)d_out;                  // 1*256*7*7*1024

  dim3 grid(POOLK, NROIS);   // (iy, roi) strips
  dim3 block(256);
  roi_pool_kernel<<<grid, block, 0, stream>>>(img, rois, out);
}